// Round 1
// 690.403 us; speedup vs baseline: 1.0649x; 1.0649x over previous
//
#include <hip/hip_runtime.h>
#include <math.h>

// Problem: J=25, F=38400, C=128, B=128 (dims derived at launch).
// x (J,F,C) fp32; idx sorted; out (J,B,C) fp32.
// Two structural HBM passes over x (491 MB > 256 MB L3) -> floor ~156 us
// at copy-BW, ~140 us at pure-read BW.
//
// R3 (discriminating experiment): rocprof top-5 shows only harness poison
// fills (1.966 GB = 4x sizeof(x), ~300 us each); every instance of our
// kernels is < 298 us. Static model says streamers should be ~80 us each.
// This round applies all remaining kernel-side levers:
//   - seg_mean: unroll x8 (8 outstanding loads/wave, 4 accumulator chains)
//   - nontemporal loads on all x traffic (evict-first, no L2 pollution)
// Prediction: if kernels dominate dur_us, >=10% drop; if the ~600 us of
// poison fills are inside the timed region, dur_us unchanged (+-2%) and we
// are already at the two-pass HBM roofline.

typedef float f4v __attribute__((ext_vector_type(4)));

__global__ void seg_bounds_kernel(const int* __restrict__ idx, int F, int B,
                                  int* __restrict__ seg) {
    int b = blockIdx.x * blockDim.x + threadIdx.x;
    if (b > B) return;
    int lo = 0, hi = F;
    while (lo < hi) {
        int mid = (lo + hi) >> 1;
        if (idx[mid] < b) lo = mid + 1; else hi = mid;
    }
    seg[b] = lo;
}

// One block per (j,b). 256 threads = 8 frame-rows x 32 lanes, float4/lane.
// Unrolled x8: frames f..f+56 step 8 per iteration, 4 accumulator chains.
__global__ void __launch_bounds__(256) seg_mean_kernel(
    const float* __restrict__ x, const int* __restrict__ seg,
    int F, int B, float* __restrict__ mean) {
    const int bid = blockIdx.x;
    const int j = bid / B, b = bid - j * B;
    const int f0 = seg[b], f1 = seg[b + 1];
    const int tid = threadIdx.x;
    const int lane32 = tid & 31;
    const int row = tid >> 5;

    const f4v* __restrict__ xp =
        (const f4v*)(x + (size_t)j * F * 128) + lane32;
    f4v a0 = {0.f, 0.f, 0.f, 0.f};
    f4v a1 = {0.f, 0.f, 0.f, 0.f};
    f4v a2 = {0.f, 0.f, 0.f, 0.f};
    f4v a3 = {0.f, 0.f, 0.f, 0.f};

    int f = f0 + row;
    const f4v* p = xp + (size_t)f * 32;
    for (; f + 56 < f1; f += 64, p += 2048) {
        f4v v0 = __builtin_nontemporal_load(p);
        f4v v1 = __builtin_nontemporal_load(p + 256);
        f4v v2 = __builtin_nontemporal_load(p + 512);
        f4v v3 = __builtin_nontemporal_load(p + 768);
        f4v v4 = __builtin_nontemporal_load(p + 1024);
        f4v v5 = __builtin_nontemporal_load(p + 1280);
        f4v v6 = __builtin_nontemporal_load(p + 1536);
        f4v v7 = __builtin_nontemporal_load(p + 1792);
        a0 += v0; a1 += v1; a2 += v2; a3 += v3;
        a0 += v4; a1 += v5; a2 += v6; a3 += v7;
    }
    for (; f < f1; f += 8, p += 256) a0 += __builtin_nontemporal_load(p);
    a0 += a1; a2 += a3; a0 += a2;

    __shared__ f4v s[256];
    s[tid] = a0;
    __syncthreads();
#pragma unroll
    for (int stride = 128; stride >= 32; stride >>= 1) {
        if (tid < stride) {
            f4v m = s[tid] + s[tid + stride];
            s[tid] = m;
        }
        __syncthreads();
    }
    if (tid < 32) {
        float inv = 1.0f / fmaxf((float)(f1 - f0), 1.0f);
        f4v m = s[tid];
        ((f4v*)(mean + ((size_t)j * B + b) * 128))[tid] = m * inv;
    }
}

// gc[r,t] = tanh(sum_k mean[r,k] * W[k,t]); W stays L2-resident.
__global__ void gc_kernel(const float* __restrict__ mean,
                          const float* __restrict__ W,
                          float* __restrict__ gc) {
    const int r = blockIdx.x;
    const int t = threadIdx.x;
    __shared__ float srow[128];
    srow[t] = mean[(size_t)r * 128 + t];
    __syncthreads();
    float acc = 0.f;
#pragma unroll 8
    for (int k = 0; k < 128; ++k) acc = fmaf(srow[k], W[k * 128 + t], acc);
    gc[(size_t)r * 128 + t] = tanhf(acc);
}

__device__ __forceinline__ float dot4(const f4v a, const f4v b) {
    return a[0] * b[0] + a[1] * b[1] + a[2] * b[2] + a[3] * b[3];
}

// One block per (j,b). Unrolled x4: 4 independent shuffle-reduce chains.
// xor masks <=16 stay within each 32-lane half of the wave, so divergent
// row-exit at segment tails is shuffle-safe.
__global__ void __launch_bounds__(256) gate_scatter_kernel(
    const float* __restrict__ x, const float* __restrict__ gc,
    const int* __restrict__ seg, int F, int B,
    float* __restrict__ out) {
    const int bid = blockIdx.x;
    const int j = bid / B, b = bid - j * B;
    const int f0 = seg[b], f1 = seg[b + 1];
    const int tid = threadIdx.x;
    const int lane32 = tid & 31;
    const int row = tid >> 5;

    const f4v* __restrict__ xp =
        (const f4v*)(x + (size_t)j * F * 128) + lane32;
    const f4v g = ((const f4v*)(gc + ((size_t)j * B + b) * 128))[lane32];

    f4v a0 = {0.f, 0.f, 0.f, 0.f};
    f4v a1 = {0.f, 0.f, 0.f, 0.f};

    int f = f0 + row;
    const f4v* p = xp + (size_t)f * 32;
    for (; f + 24 < f1; f += 32, p += 1024) {
        f4v v0 = __builtin_nontemporal_load(p);
        f4v v1 = __builtin_nontemporal_load(p + 256);
        f4v v2 = __builtin_nontemporal_load(p + 512);
        f4v v3 = __builtin_nontemporal_load(p + 768);
        float p0 = dot4(v0, g), p1 = dot4(v1, g),
              p2 = dot4(v2, g), p3 = dot4(v3, g);
#pragma unroll
        for (int m = 16; m >= 1; m >>= 1) {
            p0 += __shfl_xor(p0, m, 64);
            p1 += __shfl_xor(p1, m, 64);
            p2 += __shfl_xor(p2, m, 64);
            p3 += __shfl_xor(p3, m, 64);
        }
        float g0 = 1.0f / (1.0f + __expf(-p0));
        float g1 = 1.0f / (1.0f + __expf(-p1));
        float g2 = 1.0f / (1.0f + __expf(-p2));
        float g3 = 1.0f / (1.0f + __expf(-p3));
        a0 += g0 * v0 + g2 * v2;
        a1 += g1 * v1 + g3 * v3;
    }
    for (; f < f1; f += 8, p += 256) {
        f4v v = __builtin_nontemporal_load(p);
        float pp = dot4(v, g);
#pragma unroll
        for (int m = 16; m >= 1; m >>= 1) pp += __shfl_xor(pp, m, 64);
        float gg = 1.0f / (1.0f + __expf(-pp));
        a0 += gg * v;
    }
    a0 += a1;

    __shared__ f4v s[256];
    s[tid] = a0;
    __syncthreads();
#pragma unroll
    for (int stride = 128; stride >= 32; stride >>= 1) {
        if (tid < stride) {
            f4v m = s[tid] + s[tid + stride];
            s[tid] = m;
        }
        __syncthreads();
    }
    if (tid < 32) {
        float inv = 1.0f / fmaxf((float)(f1 - f0), 1.0f);
        f4v m = s[tid];
        ((f4v*)(out + ((size_t)j * B + b) * 128))[tid] = m * inv;
    }
}

extern "C" void kernel_launch(void* const* d_in, const int* in_sizes, int n_in,
                              void* d_out, int out_size, void* d_ws, size_t ws_size,
                              hipStream_t stream) {
    const float* x  = (const float*)d_in[0];
    const int* idx  = (const int*)d_in[1];
    const float* W  = (const float*)d_in[3];
    float* out      = (float*)d_out;

    const int F = in_sizes[1];
    int C = 1;
    while ((long long)C * C < (long long)in_sizes[3]) ++C;   // 128
    const int J = in_sizes[0] / (F * C);                     // 25
    const int B = out_size / (J * C);                        // 128

    char* ws = (char*)d_ws;
    int* seg = (int*)ws;
    size_t off = (((size_t)(B + 1) * sizeof(int)) + 255) & ~(size_t)255;
    float* mean = (float*)(ws + off);
    off += (((size_t)J * B * C * sizeof(float)) + 255) & ~(size_t)255;
    float* gcb = (float*)(ws + off);

    seg_bounds_kernel<<<(B + 1 + 255) / 256, 256, 0, stream>>>(idx, F, B, seg);
    seg_mean_kernel<<<J * B, 256, 0, stream>>>(x, seg, F, B, mean);
    gc_kernel<<<J * B, C, 0, stream>>>(mean, W, gcb);
    gate_scatter_kernel<<<J * B, 256, 0, stream>>>(x, gcb, seg, F, B, out);
}